// Round 8
// baseline (994.595 us; speedup 1.0000x reference)
//
#include <hip/hip_runtime.h>

typedef _Float16 half_t;
typedef _Float16 half4_t __attribute__((ext_vector_type(4)));
typedef _Float16 half8_t __attribute__((ext_vector_type(8)));
typedef float float4_t __attribute__((ext_vector_type(4)));

#define S_LEN 4096
#define NB 4
#define H_DIM 1024

#define MFMA16(a, b, c) __builtin_amdgcn_mfma_f32_16x16x32_f16(a, b, c, 0, 0, 0)

// LDS-only barrier (guide-verified m201 pattern): wait local (LDS) ops, then
// the compiler-visible barrier builtin. Global loads stay in flight across it.
#define BAR_LDS()                                      \
  do {                                                 \
    asm volatile("s_waitcnt lgkmcnt(0)" ::: "memory"); \
    __builtin_amdgcn_s_barrier();                      \
  } while (0)

// ---------------------------------------------------------------------------
// Kernel 0: transpose + fp16-split W -> Wt_hi/Wt_lo [h][f] (scratch in d_out;
// flash_attn overwrites all of d_out afterwards).
// ---------------------------------------------------------------------------
__global__ __launch_bounds__(256) void wt_prep(
    const float* __restrict__ Wq, const float* __restrict__ Wk,
    const float* __restrict__ Wv, half_t* __restrict__ wth,
    half_t* __restrict__ wtl) {
  const int zi = blockIdx.z;
  const float* W = (zi == 0) ? Wq : (zi == 1) ? Wk : Wv;
  half_t* oh = wth + (size_t)zi * H_DIM * H_DIM;
  half_t* ol = wtl + (size_t)zi * H_DIM * H_DIM;
  const int h0 = blockIdx.x * 32, f0 = blockIdx.y * 32;
  __shared__ float Ws[32][33];
  const int t = threadIdx.x;
  const int c = t & 31, r8 = t >> 5;
#pragma unroll
  for (int rr = 0; rr < 4; rr++)
    Ws[r8 * 4 + rr][c] = W[(size_t)(f0 + r8 * 4 + rr) * H_DIM + h0 + c];
  __syncthreads();
#pragma unroll
  for (int rr = 0; rr < 4; rr++) {
    int h = r8 * 4 + rr;
    float v = Ws[c][h];
    half_t hi = (half_t)v;
    half_t lo = (half_t)(v - (float)hi);
    oh[(size_t)(h0 + h) * H_DIM + f0 + c] = hi;
    ol[(size_t)(h0 + h) * H_DIM + f0 + c] = lo;
  }
}

// ---------------------------------------------------------------------------
// Kernel 1: QKV projection on MFMA, 3-term fp16 split (hh + lh + hl).
// 256x256 tiles (512 threads, 8 waves), dim3(12, 64), double-buffered Bs
// pipeline (round-7, verified). This round: zi=2 (V^T) epilogue rewritten —
// was 128 scalar 2B stores/lane at 8KB stride (uncoalesced); now transposed
// through the free Bs LDS and stored as coalesced half8 rows.
// ---------------------------------------------------------------------------
#define QKV_BK 64

__global__ __launch_bounds__(512, 2) void qkv_mfma(
    const float* __restrict__ x, const half_t* __restrict__ wth,
    const half_t* __restrict__ wtl, const float* __restrict__ bq,
    const float* __restrict__ bk, const float* __restrict__ bv,
    half_t* __restrict__ ws) {
  const int bx = blockIdx.x;        // 0..11 = zi*4 + h-tile
  const int zi = bx >> 2;
  const int m0 = (bx & 3) * 256;    // h-tile base within zi
  const int n0 = blockIdx.y * 256;  // flattened b*s tile base
  const half_t* Ah_g = wth + (size_t)zi * H_DIM * H_DIM;
  const half_t* Al_g = wtl + (size_t)zi * H_DIM * H_DIM;
  const float* bias = (zi == 0) ? bq : (zi == 1) ? bk : bv;
  half_t* out = ws + (size_t)zi * ((size_t)NB * S_LEN * H_DIM);
  const int t = threadIdx.x;
  const int w = t >> 6, lane = t & 63, ln = lane & 15, quad = lane >> 4;

  __shared__ half_t Bs[2][32768];  // per buf: hi[16384] | lo[16384] = 64 KB

  float4_t acc[2][16] = {};

  const int ss = t >> 1;        // 0..255: s-row within tile
  const int fh = (t & 1) * 32;  // k-col half
  const int snt = ss >> 4, sln = ss & 15;

  const float* xrow = x + (size_t)(n0 + ss) * H_DIM + fh;

  // ---- prologue: load x(0), convert, write Bs[0] ----
  float4 xr[8];
#pragma unroll
  for (int g = 0; g < 4; g++) {
    xr[2 * g] = *(const float4*)(xrow + g * 8);
    xr[2 * g + 1] = *(const float4*)(xrow + g * 8 + 4);
  }
#pragma unroll
  for (int g = 0; g < 4; g++) {
    float vv[8] = {xr[2 * g].x,     xr[2 * g].y,     xr[2 * g].z,
                   xr[2 * g].w,     xr[2 * g + 1].x, xr[2 * g + 1].y,
                   xr[2 * g + 1].z, xr[2 * g + 1].w};
    half8_t hhi, hlo;
#pragma unroll
    for (int j = 0; j < 8; j++) {
      half_t h = (half_t)vv[j];
      hhi[j] = h;
      hlo[j] = (half_t)(vv[j] - (float)h);
    }
    int f = fh + g * 8;
    int k2 = f >> 5, qd = (f >> 3) & 3;
    int base = ((k2 * 16 + snt) * 64 + qd * 16 + sln) * 8;
    *(half8_t*)&Bs[0][base] = hhi;
    *(half8_t*)&Bs[0][16384 + base] = hlo;
  }

  for (int it = 0; it < 16; it++) {
    const int k0 = it * QKV_BK;
    const int cur = it & 1;
    const bool more = (it < 15);

    // issue A-frags(it) — consumed in MFMA right after the barrier
    half8_t ah[2][2], al[2][2];
#pragma unroll
    for (int i = 0; i < 2; i++) {
      const size_t arow =
          (size_t)(m0 + w * 32 + i * 16 + ln) * H_DIM + k0 + quad * 8;
#pragma unroll
      for (int k2 = 0; k2 < 2; k2++) {
        ah[i][k2] = *(const half8_t*)(Ah_g + arow + k2 * 32);
        al[i][k2] = *(const half8_t*)(Al_g + arow + k2 * 32);
      }
    }
    // issue x(it+1) — consumed after MFMA (full-MFMA cover)
    if (more) {
      const float* xp = xrow + (k0 + QKV_BK);
#pragma unroll
      for (int g = 0; g < 4; g++) {
        xr[2 * g] = *(const float4*)(xp + g * 8);
        xr[2 * g + 1] = *(const float4*)(xp + g * 8 + 4);
      }
    }

    BAR_LDS();  // Bs[cur] complete (all waves); globals stay in flight

#pragma unroll
    for (int k2 = 0; k2 < 2; k2++) {
#pragma unroll
      for (int nt = 0; nt < 16; nt++) {
        int base = ((k2 * 16 + nt) * 64 + lane) * 8;
        half8_t bh = *(const half8_t*)&Bs[cur][base];
        half8_t bl = *(const half8_t*)&Bs[cur][16384 + base];
        acc[0][nt] = MFMA16(ah[0][k2], bh, acc[0][nt]);
        acc[1][nt] = MFMA16(ah[1][k2], bh, acc[1][nt]);
        acc[0][nt] = MFMA16(al[0][k2], bh, acc[0][nt]);
        acc[1][nt] = MFMA16(al[1][k2], bh, acc[1][nt]);
        acc[0][nt] = MFMA16(ah[0][k2], bl, acc[0][nt]);
        acc[1][nt] = MFMA16(ah[1][k2], bl, acc[1][nt]);
      }
    }

    // convert + write next buffer (x loads covered by the MFMA block above)
    if (more) {
#pragma unroll
      for (int g = 0; g < 4; g++) {
        float vv[8] = {xr[2 * g].x,     xr[2 * g].y,     xr[2 * g].z,
                       xr[2 * g].w,     xr[2 * g + 1].x, xr[2 * g + 1].y,
                       xr[2 * g + 1].z, xr[2 * g + 1].w};
        half8_t hhi, hlo;
#pragma unroll
        for (int j = 0; j < 8; j++) {
          half_t h = (half_t)vv[j];
          hhi[j] = h;
          hlo[j] = (half_t)(vv[j] - (float)h);
        }
        int f = fh + g * 8;
        int k2 = f >> 5, qd = (f >> 3) & 3;
        int base = ((k2 * 16 + snt) * 64 + qd * 16 + sln) * 8;
        *(half8_t*)&Bs[cur ^ 1][base] = hhi;
        *(half8_t*)&Bs[cur ^ 1][16384 + base] = hlo;
      }
    }
  }

  const float oscale = (zi == 0) ? 0.03125f : 1.0f;
  float bb[2][4];
#pragma unroll
  for (int i = 0; i < 2; i++)
#pragma unroll
    for (int r = 0; r < 4; r++)
      bb[i][r] = bias[m0 + w * 32 + i * 16 + quad * 4 + r];

  if (zi < 2) {
#pragma unroll
    for (int i = 0; i < 2; i++)
#pragma unroll
      for (int nt = 0; nt < 16; nt++) {
        half4_t h4;
#pragma unroll
        for (int r = 0; r < 4; r++)
          h4[r] = (half_t)((acc[i][nt][r] + bb[i][r]) * oscale);
        size_t s = n0 + nt * 16 + ln;
        *(half4_t*)&out[s * H_DIM + m0 + w * 32 + i * 16 + quad * 4] = h4;
      }
  } else {
    // V^T store via LDS transpose: coalesced half8 row stores.
    // BsT = 128 rows x 264 (padded) halfs = 33792 <= 65536 total Bs halfs.
    half_t* BsT = &Bs[0][0];
    const int bti = n0 >> 12;         // batch index
    const int sb = n0 & (S_LEN - 1);  // si base within batch
#pragma unroll
    for (int i = 0; i < 2; i++) {
      BAR_LDS();  // prior Bs readers (MFMA / prev pass) done
#pragma unroll
      for (int nt = 0; nt < 16; nt++)
#pragma unroll
        for (int r = 0; r < 4; r++)
          BsT[(w * 16 + quad * 4 + r) * 264 + nt * 16 + ln] =
              (half_t)(acc[i][nt][r] + bb[i][r]);
      BAR_LDS();
#pragma unroll
      for (int c2 = 0; c2 < 8; c2++) {
        int idx = c2 * 512 + t;  // 0..4095
        int rl = idx >> 5, ch = idx & 31;
        half8_t v = *(half8_t*)&BsT[rl * 264 + ch * 8];
        int h = m0 + (rl >> 4) * 32 + i * 16 + (rl & 15);
        *(half8_t*)&out[((size_t)bti * H_DIM + h) * S_LEN + sb + ch * 8] = v;
      }
    }
  }
}

// ---------------------------------------------------------------------------
// Kernel 2: MFMA flash attention, TQ=64 (512 threads, 8 waves, 1 block/CU).
// Round-3 verified structure + this round: PACING BARRIER every 4 K/V tiles.
// Rationale: each XCD's 32 blocks stream the SAME 16.8 MB batch K/V in the
// same order; measured effective BW == L3 plateau => zero L2 reuse (blocks
// drifted apart). Aligning blocks within a 2 MB window (4 tiles <= 4 MB L2)
// turns 31/32 of K/V reads into L2 hits. Ticket barrier: atomicAdd + bounded
// relaxed spin (pacing-only -> correctness never depends on it; bounded spin
// -> deadlock impossible). Counter at d_out+48MB (wt scratch is first 12MB;
// epilogue overwrite provably after last ticket), reset via hipMemsetAsync.
// LDS: Qs 128 KB + Ps 16 KB + wmax/wl 4 KB.
// ---------------------------------------------------------------------------
#define TQ 64
#define TK 128

__global__ __launch_bounds__(512, 2) void flash_attn(
    const half_t* __restrict__ qw, const half_t* __restrict__ kw,
    const half_t* __restrict__ vt, unsigned* __restrict__ pace,
    float* __restrict__ out) {
  // batch -> 2 XCDs; 32 blocks/XCD share one K/V stream, 1 block/CU.
  const int slot = blockIdx.x & 7;
  const int b = slot >> 1;
  const int qb = ((blockIdx.x >> 3) << 1) | (slot & 1);
  const int q0 = qb * TQ;
  const int t = threadIdx.x;
  const int w = t >> 6;
  const int lane = t & 63;
  const int ln = lane & 15;
  const int quad = lane >> 4;

  __shared__ half_t Qs[65536];  // [rs(4)][ks(32)][lane(64)][8] = 128 KB
  __shared__ half_t Ps[8192];   // [rs(4)][kc(4)][lane(64)][8] = 16 KB
  __shared__ float wmax[8][64];
  __shared__ float wl[8][64];

  const half_t* qp = qw + ((size_t)b * S_LEN + q0) * H_DIM;
  const half_t* kbp = kw + (size_t)b * S_LEN * H_DIM;
  const half_t* vbt = vt + (size_t)b * H_DIM * S_LEN;

  // K ring prologue for kt=0 (issued before Q staging so it lands early)
  const half_t* kr = kbp + (size_t)(w * 16 + ln) * H_DIM + quad * 8;
  half8_t kbuf[6];
#pragma unroll
  for (int d = 0; d < 6; d++) kbuf[d] = *(const half8_t*)(kr + d * 32);

  // stage Q tile into fragment order
#pragma unroll
  for (int i = 0; i < 16; i++) {
    int flat = t * 8 + i * 4096;
    int r = flat >> 10, c = flat & 1023;
    int rs = r >> 4, lq = r & 15, ks = c >> 5, qd = (c >> 3) & 3;
    *(half8_t*)&Qs[((rs * 32 + ks) * 64 + qd * 16 + lq) * 8] =
        *(const half8_t*)&qp[(size_t)r * H_DIM + c];
  }
  BAR_LDS();

  // per-lane softmax running state, lane <-> q row (all waves redundant)
  float m_l = -1e30f;
  float l_l = 0.0f;

  float4_t O[4][8] = {};  // [rs(4 row-tiles)][j(8 col-tiles in h-chunk w)]

  for (int kt = 0; kt < S_LEN; kt += TK) {
    // ---------------- phase A: S = Q . K^T ----------------
    float4_t s[4] = {};
    __builtin_amdgcn_s_setprio(1);
#pragma unroll
    for (int ks = 0; ks < 32; ks++) {
      half8_t a0 = *(const half8_t*)&Qs[(ks * 64 + lane) * 8];
      half8_t a1 = *(const half8_t*)&Qs[16384 + (ks * 64 + lane) * 8];
      half8_t a2 = *(const half8_t*)&Qs[32768 + (ks * 64 + lane) * 8];
      half8_t a3 = *(const half8_t*)&Qs[49152 + (ks * 64 + lane) * 8];
      half8_t kc = kbuf[ks % 6];
      if (ks < 26) kbuf[ks % 6] = *(const half8_t*)(kr + (ks + 6) * 32);
      s[0] = MFMA16(a0, kc, s[0]);
      s[1] = MFMA16(a1, kc, s[1]);
      s[2] = MFMA16(a2, kc, s[2]);
      s[3] = MFMA16(a3, kc, s[3]);
    }
    __builtin_amdgcn_s_setprio(0);

    // K prefetch for NEXT tile — in flight across softmax + phase C
    kr += (size_t)TK * H_DIM;
    if (kt + TK < S_LEN) {
#pragma unroll
      for (int d = 0; d < 6; d++) kbuf[d] = *(const half8_t*)(kr + d * 32);
    }

    // V ring prefetch (j=0..3 of kc=0) — in flight across softmax
    const half_t* vbase = vbt + (size_t)(w * 128 + ln) * S_LEN + kt + quad * 8;
    half8_t vr[4];
#pragma unroll
    for (int j = 0; j < 4; j++)
      vr[j] = *(const half8_t*)(vbase + (size_t)j * 16 * S_LEN);

    // ---------------- softmax stats ----------------
    float rm[4][4];
#pragma unroll
    for (int rs = 0; rs < 4; rs++)
#pragma unroll
      for (int r = 0; r < 4; r++) rm[rs][r] = s[rs][r];
#pragma unroll
    for (int off = 1; off < 16; off <<= 1)
#pragma unroll
      for (int rs = 0; rs < 4; rs++)
#pragma unroll
        for (int r = 0; r < 4; r++)
          rm[rs][r] = fmaxf(rm[rs][r], __shfl_xor(rm[rs][r], off));
    if (ln == 0)
#pragma unroll
      for (int rs = 0; rs < 4; rs++)
#pragma unroll
        for (int r = 0; r < 4; r++)
          wmax[w][rs * 16 + quad * 4 + r] = rm[rs][r];
    BAR_LDS();  // W1

    float nm_l = m_l;
#pragma unroll
    for (int w2 = 0; w2 < 8; w2++) nm_l = fmaxf(nm_l, wmax[w2][lane]);
    float aS_l = __expf(m_l - nm_l);
    m_l = nm_l;

    // ---- P = exp(S - m) -> Ps (fragment order), O rescale fused ----
    const int pbase = (w >> 1) * 512 + (w & 1) * 256 + (ln >> 3) * 128 +
                      quad * 32 + (ln & 7);
    float pl[4][4];
#pragma unroll
    for (int rs = 0; rs < 4; rs++)
#pragma unroll
      for (int r = 0; r < 4; r++) {
        const int q = rs * 16 + quad * 4 + r;
        float nmq = __shfl(m_l, q);
        float aq = __shfl(aS_l, q);
        float p = __expf(s[rs][r] - nmq);
        pl[rs][r] = p;
        Ps[pbase + rs * 2048 + r * 8] = (half_t)p;
#pragma unroll
        for (int j = 0; j < 8; j++) O[rs][j][r] *= aq;
      }
#pragma unroll
    for (int off = 1; off < 16; off <<= 1)
#pragma unroll
      for (int rs = 0; rs < 4; rs++)
#pragma unroll
        for (int r = 0; r < 4; r++) pl[rs][r] += __shfl_xor(pl[rs][r], off);
    if (ln == 0)
#pragma unroll
      for (int rs = 0; rs < 4; rs++)
#pragma unroll
        for (int r = 0; r < 4; r++)
          wl[w][rs * 16 + quad * 4 + r] = pl[rs][r];
    BAR_LDS();  // W2

    float s8_l = 0.f;
#pragma unroll
    for (int w2 = 0; w2 < 8; w2++) s8_l += wl[w2][lane];
    l_l = l_l * aS_l + s8_l;

    // ---------------- phase C: O += P @ V (kc-major) ----------------
#pragma unroll
    for (int kc = 0; kc < 4; kc++) {
      half8_t pa[4];
#pragma unroll
      for (int rs = 0; rs < 4; rs++)
        pa[rs] = *(const half8_t*)&Ps[((rs * 4 + kc) * 64 + lane) * 8];
      __builtin_amdgcn_s_setprio(1);
#pragma unroll
      for (int j = 0; j < 8; j++) {
        half8_t vc = vr[j & 3];
        const int jn = j + 4;
        if (jn < 8) {
          vr[j & 3] =
              *(const half8_t*)(vbase + (size_t)jn * 16 * S_LEN + kc * 32);
        } else if (kc < 3) {
          vr[j & 3] = *(const half8_t*)(vbase + (size_t)(jn - 8) * 16 * S_LEN +
                                        (kc + 1) * 32);
        }
#pragma unroll
        for (int rs = 0; rs < 4; rs++)
          O[rs][j] = MFMA16(pa[rs], vc, O[rs][j]);
      }
      __builtin_amdgcn_s_setprio(0);
    }

    // ---------------- pacing barrier (every 4 tiles, not last) -----------
    if ((((kt >> 7) & 3) == 3) && (kt + TK < S_LEN)) {
      if (t == 0) {
        unsigned ticket = atomicAdd(pace, 1u);
        unsigned target = ((ticket >> 8) + 1u) << 8;
        int spin = 0;
        while (__hip_atomic_load(pace, __ATOMIC_RELAXED,
                                 __HIP_MEMORY_SCOPE_AGENT) < target &&
               spin < 300)
          spin++;
      }
      // block-wide effect propagates via next tile's W1 barrier
    }
  }

  // ---------------- epilogue ----------------
  float il[4][4];
#pragma unroll
  for (int rs = 0; rs < 4; rs++)
#pragma unroll
    for (int r = 0; r < 4; r++)
      il[rs][r] = 1.0f / __shfl(l_l, rs * 16 + quad * 4 + r);
  float* ob = out + ((size_t)b * S_LEN + q0) * H_DIM + w * 128 + ln;
#pragma unroll
  for (int rs = 0; rs < 4; rs++)
#pragma unroll
    for (int j = 0; j < 8; j++)
#pragma unroll
      for (int r = 0; r < 4; r++)
        ob[(size_t)(rs * 16 + quad * 4 + r) * H_DIM + j * 16] =
            O[rs][j][r] * il[rs][r];
}

// ---------------------------------------------------------------------------
extern "C" void kernel_launch(void* const* d_in, const int* in_sizes, int n_in,
                              void* d_out, int out_size, void* d_ws,
                              size_t ws_size, hipStream_t stream) {
  const float* x = (const float*)d_in[0];
  const float* Wq = (const float*)d_in[1];
  const float* bq = (const float*)d_in[2];
  const float* Wk = (const float*)d_in[3];
  const float* bk = (const float*)d_in[4];
  const float* Wv = (const float*)d_in[5];
  const float* bv = (const float*)d_in[6];
  half_t* ws = (half_t*)d_ws;  // q(32MB) | k(32MB) | vt(32MB, transposed)
  float* out = (float*)d_out;

  half_t* wth = (half_t*)d_out;  // scratch; overwritten by flash_attn
  half_t* wtl = wth + (size_t)3 * H_DIM * H_DIM;

  // pacing counter: inside d_out at +48MB (wt scratch ends at 12MB; final
  // output overwrites it only after all tickets are issued — safe).
  unsigned* pace = (unsigned*)((char*)d_out + (size_t)48 * 1024 * 1024);

  wt_prep<<<dim3(32, 32, 3), 256, 0, stream>>>(Wq, Wk, Wv, wth, wtl);

  qkv_mfma<<<dim3(12, 64), 512, 0, stream>>>(x, wth, wtl, bq, bk, bv, ws);

  hipMemsetAsync(pace, 0, sizeof(unsigned), stream);

  const half_t* qw = ws;
  const half_t* kw = ws + (size_t)NB * S_LEN * H_DIM;
  const half_t* vt = ws + 2 * (size_t)NB * S_LEN * H_DIM;
  flash_attn<<<dim3((S_LEN / TQ) * NB), 512, 0, stream>>>(qw, kw, vt, pace,
                                                          out);
}